// Round 1
// baseline (442.680 us; speedup 1.0000x reference)
//
#include <hip/hip_runtime.h>
#include <stdint.h>

#define O_DIM 2048
#define I_DIM 4096
#define BS_TOK 8192   // 4*2048 tokens
#define KCB 256
#define PQD 8

typedef __attribute__((ext_vector_type(8))) __bf16 bf16x8;
typedef __attribute__((ext_vector_type(4))) float f32x4;

static __device__ __forceinline__ unsigned short f32_to_bf16(float f) {
    unsigned int u = __float_as_uint(f);
    u += 0x7fffu + ((u >> 16) & 1u);   // round-to-nearest-even
    return (unsigned short)(u >> 16);
}

static __device__ __forceinline__ unsigned int pack2(unsigned short lo, unsigned short hi) {
    return (unsigned int)lo | ((unsigned int)hi << 16);
}

// ---------------- 1. fused rowscale + assignment, 4 groups/thread ----------------
// (unchanged from round-2-verified version)
#define TAU 1.5e-4f
#define CUT 3.0e-4f

__global__ __launch_bounds__(256) void fused_assign_kernel(const float* __restrict__ weight,
                                                           const float* __restrict__ codebook,
                                                           unsigned short* __restrict__ wq) {
    __shared__ __align__(16) float cb[KCB * PQD];   // 8 KB
    __shared__ float n2[KCB];                       // 1 KB
    __shared__ float red[4];

    const int t = threadIdx.x;
    const int half = t >> 7;
    const int tid = t & 127;
    const int o = blockIdx.x * 2 + half;

    const float* wp = weight + (size_t)o * I_DIM + tid * 32;
    float w[32];
#pragma unroll
    for (int q = 0; q < 8; ++q) {
        float4 v = *(const float4*)(wp + q * 4);
        w[q * 4 + 0] = v.x; w[q * 4 + 1] = v.y; w[q * 4 + 2] = v.z; w[q * 4 + 3] = v.w;
    }

    float4 c0 = *(const float4*)(codebook + t * PQD);
    float4 c1 = *(const float4*)(codebook + t * PQD + 4);
    *(float4*)&cb[t * PQD]     = c0;
    *(float4*)&cb[t * PQD + 4] = c1;
    double n2d = 0.0;
    n2d = fma((double)c0.x, (double)c0.x, n2d); n2d = fma((double)c0.y, (double)c0.y, n2d);
    n2d = fma((double)c0.z, (double)c0.z, n2d); n2d = fma((double)c0.w, (double)c0.w, n2d);
    n2d = fma((double)c1.x, (double)c1.x, n2d); n2d = fma((double)c1.y, (double)c1.y, n2d);
    n2d = fma((double)c1.z, (double)c1.z, n2d); n2d = fma((double)c1.w, (double)c1.w, n2d);
    n2[t] = (float)n2d;

    float m = 0.f;
#pragma unroll
    for (int i = 0; i < 32; ++i) m = fmaxf(m, fabsf(w[i]));
#pragma unroll
    for (int off = 32; off > 0; off >>= 1)
        m = fmaxf(m, __shfl_down(m, off, 64));
    int wave = t >> 6, lane = t & 63;
    if (lane == 0) red[wave] = m;
    __syncthreads();
    float s = fmaxf(fmaxf(red[half * 2], red[half * 2 + 1]), 1e-6f);

    float best[4] = {1e30f, 1e30f, 1e30f, 1e30f};
    float sec[4]  = {1e30f, 1e30f, 1e30f, 1e30f};
    int bi[4] = {0, 0, 0, 0};
#pragma unroll 2
    for (int c = 0; c < KCB; ++c) {
        float4 p0 = *(const float4*)&cb[c * PQD];
        float4 p1 = *(const float4*)&cb[c * PQD + 4];
        float t1 = s * n2[c];
#pragma unroll
        for (int k = 0; k < 4; ++k) {
            const float* wk = w + k * 8;
            float d = 0.f;
            d = fmaf(p0.x, wk[0], d); d = fmaf(p0.y, wk[1], d);
            d = fmaf(p0.z, wk[2], d); d = fmaf(p0.w, wk[3], d);
            d = fmaf(p1.x, wk[4], d); d = fmaf(p1.y, wk[5], d);
            d = fmaf(p1.z, wk[6], d); d = fmaf(p1.w, wk[7], d);
            float e = fmaf(-2.f, d, t1);
            bool lt = e < best[k];
            sec[k] = fminf(sec[k], lt ? best[k] : e);
            best[k] = fminf(best[k], e);
            bi[k] = lt ? c : bi[k];
        }
    }

#pragma unroll
    for (int k = 0; k < 4; ++k) {
        if (sec[k] - best[k] < TAU) {
            const float* wk = w + k * 8;
            double sd = (double)s;
            double g[PQD];
#pragma unroll
            for (int d = 0; d < PQD; ++d) g[d] = (double)wk[d] / sd;
            double bb = 1e300; int bbi = 0;
            float cut = best[k] + CUT;
            for (int c = 0; c < KCB; ++c) {
                float4 p0 = *(const float4*)&cb[c * PQD];
                float4 p1 = *(const float4*)&cb[c * PQD + 4];
                float d0 = 0.f;
                d0 = fmaf(p0.x, wk[0], d0); d0 = fmaf(p0.y, wk[1], d0);
                d0 = fmaf(p0.z, wk[2], d0); d0 = fmaf(p0.w, wk[3], d0);
                d0 = fmaf(p1.x, wk[4], d0); d0 = fmaf(p1.y, wk[5], d0);
                d0 = fmaf(p1.z, wk[6], d0); d0 = fmaf(p1.w, wk[7], d0);
                float e0 = fmaf(-2.f, d0, s * n2[c]);
                if (e0 <= cut) {
                    double n = 0.0, dot = 0.0;
#pragma unroll
                    for (int d = 0; d < PQD; ++d) {
                        double cv = (double)cb[c * PQD + d];
                        n = fma(cv, cv, n);
                        dot = fma(cv, g[d], dot);
                    }
                    double d2 = fma(-2.0, dot, n);
                    if (d2 < bb) { bb = d2; bbi = c; }
                }
            }
            bi[k] = bbi;
        }
    }

    unsigned short* dst = wq + (size_t)o * I_DIM + tid * 32;
#pragma unroll
    for (int k = 0; k < 4; ++k) {
        unsigned short u[8];
#pragma unroll
        for (int d = 0; d < PQD; ++d) u[d] = f32_to_bf16(cb[bi[k] * PQD + d] * s);
        uint4 r;
        r.x = pack2(u[0], u[1]); r.y = pack2(u[2], u[3]);
        r.z = pack2(u[4], u[5]); r.w = pack2(u[6], u[7]);
        *(uint4*)(dst + k * 8) = r;
    }
}

// ---------------- 2. x fp32 -> bf16 ----------------
__global__ __launch_bounds__(256) void convert_kernel(const float* __restrict__ x,
                                                      unsigned short* __restrict__ xb) {
    size_t i = ((size_t)blockIdx.x * 256 + threadIdx.x) * 8;
    float4 v0 = *(const float4*)(x + i);
    float4 v1 = *(const float4*)(x + i + 4);
    uint4 r;
    r.x = pack2(f32_to_bf16(v0.x), f32_to_bf16(v0.y));
    r.y = pack2(f32_to_bf16(v0.z), f32_to_bf16(v0.w));
    r.z = pack2(f32_to_bf16(v1.x), f32_to_bf16(v1.y));
    r.w = pack2(f32_to_bf16(v1.z), f32_to_bf16(v1.w));
    *(uint4*)(xb + i) = r;
}

// ---------------- 3. 256x256 8-phase bf16 MFMA GEMM + bias ----------------
// Port of the verified 8-phase template (T1+T2+T3+T4+T5):
//  - BM=BN=256, K-tile=64, 2 tiles/iter, 8 waves (2Mx4N), per-wave C = 128x64
//  - 128 KiB LDS double buffer; global_load_lds w=16 with XOR-pre-swizzled
//    global source (LDS chunk c of row r holds global 16B-chunk c^(r&7));
//    ds_read_b128 reads chunk (kk*4+q)^(lr&7) -> ~2-way bank aliasing (free)
//  - raw s_barrier (no vmcnt drain); counted s_waitcnt vmcnt(4) at ends of
//    phases 3 and 7 only -> 4 loads always in flight across waits
//  - stage schedule (iter i; E=2i in buf0, O=2i+1 in buf1):
//      P0: O.A0->buf1   P1: O.A1->buf1, (E+2).B0->buf0   P2: (E+2).B1->buf0
//      P3: -            P4: (E+2).A0->buf0   P5: (E+2).A1->buf0
//      P6: (O+2).B0->buf1   P7: (O+2).B1->buf1
//    each stage target region was fully read in an earlier (barrier-closed)
//    phase; each staged tile lands before the vmcnt(4) that covers it.
#define GBM 256
#define GBN 256
#define NIT 32   // 32 iters x 2 K-tiles x 64 = 4096

#define LOFF_A(b,h) ((b)*32768 + (h)*8192)
#define LOFF_B(b,h) ((b)*32768 + 16384 + (h)*8192)

#define BARX() asm volatile("s_barrier" ::: "memory")
#define WAITV(n) asm volatile("s_waitcnt vmcnt(" #n ")" ::: "memory")

#define STAGE(P, h, kt, loff)                                                       \
  { _Pragma("unroll")                                                               \
    for (int l_ = 0; l_ < 2; ++l_) {                                                \
      const unsigned short* g_ = (P) + (size_t)((h) * 128 + l_ * 64) * I_DIM + (size_t)(kt) * 64; \
      unsigned short* d_ = (unsigned short*)&lds[(loff) + l_ * 4096 + wave * 512];  \
      __builtin_amdgcn_global_load_lds((const __attribute__((address_space(1))) void*)g_, \
                                       (__attribute__((address_space(3))) void*)d_, 16, 0, 0); \
    } }

#define READ_B(boff)                                                                \
  { _Pragma("unroll")                                                               \
    for (int kk_ = 0; kk_ < 2; ++kk_) {                                             \
      _Pragma("unroll")                                                             \
      for (int j_ = 0; j_ < 4; ++j_)                                                \
        bf[kk_][j_] = *(const bf16x8*)&lds[(boff) + baseB + j_ * 1024 + cxo[kk_]];  \
    } }

#define READ_A(boff, p)                                                             \
  { _Pragma("unroll")                                                               \
    for (int kk_ = 0; kk_ < 2; ++kk_) {                                             \
      _Pragma("unroll")                                                             \
      for (int ii_ = 0; ii_ < 2; ++ii_)                                             \
        af[kk_][ii_] = *(const bf16x8*)&lds[(boff) + baseA + (2 * (p) + ii_) * 1024 + cxo[kk_]]; \
    } }

#define MFMA_Q(p)                                                                   \
  { __builtin_amdgcn_s_setprio(1);                                                  \
    _Pragma("unroll")                                                               \
    for (int ii_ = 0; ii_ < 2; ++ii_) {                                             \
      _Pragma("unroll")                                                             \
      for (int j_ = 0; j_ < 4; ++j_) {                                              \
        _Pragma("unroll")                                                           \
        for (int kk_ = 0; kk_ < 2; ++kk_)                                           \
          acc[2 * (p) + ii_][j_] = __builtin_amdgcn_mfma_f32_16x16x32_bf16(         \
              af[kk_][ii_], bf[kk_][j_], acc[2 * (p) + ii_][j_], 0, 0, 0);          \
      }                                                                             \
    }                                                                               \
    __builtin_amdgcn_s_setprio(0); }

__global__ __launch_bounds__(512, 2) void gemm_8phase(const unsigned short* __restrict__ A, // [BS_TOK][I]
                                                      const unsigned short* __restrict__ B, // [O_DIM][I]
                                                      const float* __restrict__ bias,
                                                      float* __restrict__ C) {
    __shared__ __align__(16) unsigned short lds[65536];   // 128 KiB: 2 bufs x (A 256x64 + B 256x64)

    const int t = threadIdx.x;
    const int wave = t >> 6;
    const int lane = t & 63;
    const int q = lane >> 4;
    const int lr = lane & 15;
    const int wr = wave >> 2;   // 0..1 (M)
    const int wc = wave & 3;    // 0..3 (N)

    // bijective XCD swizzle: 256 wgs, XCD x owns column-panel tn=x (B panel 2MB -> L2)
    const int swz = (((int)blockIdx.x & 7) * 32) + ((int)blockIdx.x >> 3);
    const int bm = (swz & 31) * GBM;
    const int bn = (swz >> 5) * GBN;

    // staging: thread t covers row (l*64 + t/8), 16B chunk (t%8); source chunk
    // pre-swizzled by ^(row&7) so LDS stays linear (rule #21)
    const int trow = t >> 3;
    const int csw = ((t & 7) ^ (trow & 7)) * 8;
    const unsigned short* pa = A + (size_t)(bm + trow) * I_DIM + csw;
    const unsigned short* pb = B + (size_t)(bn + trow) * I_DIM + csw;

    // read bases (shorts)
    const int baseA = wr * 8192 + lr * 64;
    const int baseB = 16384 + (wc >> 1) * 8192 + ((wc & 1) * 64 + lr) * 64;
    const int cxo[2] = { (q ^ (lr & 7)) * 8, ((4 + q) ^ (lr & 7)) * 8 };

    f32x4 acc[8][4] = {};
    bf16x8 bf[2][4];
    bf16x8 af[2][2];

    // ---- prologue: tile0 (buf0, 4 halves) + tile1.B (buf1) ----
    STAGE(pa, 0, 0, LOFF_A(0, 0));
    STAGE(pa, 1, 0, LOFF_A(0, 1));
    STAGE(pb, 0, 0, LOFF_B(0, 0));
    STAGE(pb, 1, 0, LOFF_B(0, 1));
    STAGE(pb, 0, 1, LOFF_B(1, 0));
    STAGE(pb, 1, 1, LOFF_B(1, 1));
    WAITV(4);          // tile0 landed; tile1.B (4 loads) stays in flight
    BARX();

#pragma unroll 1
    for (int i = 0; i < NIT; ++i) {
        const int kO  = 2 * i + 1;
        const int kN  = 2 * i + 2;
        const int kN1 = 2 * i + 3;
        const bool nl = (i < NIT - 1);

        // P0: tile E quad0 (buf0); stage O.A0 -> buf1.A0
        READ_B(0);
        READ_A(0, 0);
        STAGE(pa, 0, kO, LOFF_A(1, 0));
        BARX();
        MFMA_Q(0);
        BARX();

        // P1: quad1; stage O.A1 -> buf1.A1 ; (E+2).B0 -> buf0.B0
        READ_A(0, 1);
        STAGE(pa, 1, kO, LOFF_A(1, 1));
        if (nl) STAGE(pb, 0, kN, LOFF_B(0, 0));
        BARX();
        MFMA_Q(1);
        BARX();

        // P2: quad2; stage (E+2).B1 -> buf0.B1
        READ_A(0, 2);
        if (nl) STAGE(pb, 1, kN, LOFF_B(0, 1));
        BARX();
        MFMA_Q(2);
        BARX();

        // P3: quad3; counted wait covers tile O (A+B landed)
        READ_A(0, 3);
        BARX();
        MFMA_Q(3);
        if (nl) { WAITV(4); } else { WAITV(0); }
        BARX();

        // P4: tile O quad0 (buf1); stage (E+2).A0 -> buf0.A0
        READ_B(32768);
        READ_A(32768, 0);
        if (nl) STAGE(pa, 0, kN, LOFF_A(0, 0));
        BARX();
        MFMA_Q(0);
        BARX();

        // P5: quad1; stage (E+2).A1 -> buf0.A1
        READ_A(32768, 1);
        if (nl) STAGE(pa, 1, kN, LOFF_A(0, 1));
        BARX();
        MFMA_Q(1);
        BARX();

        // P6: quad2; stage (O+2).B0 -> buf1.B0
        READ_A(32768, 2);
        if (nl) STAGE(pb, 0, kN1, LOFF_B(1, 0));
        BARX();
        MFMA_Q(2);
        BARX();

        // P7: quad3; counted wait covers tile E+2 (buf0 complete)
        READ_A(32768, 3);
        if (nl) STAGE(pb, 1, kN1, LOFF_B(1, 1));
        BARX();
        MFMA_Q(3);
        WAITV(4);   // no-op on last iter (0 outstanding)
        BARX();
    }

    // ---- epilogue: C = acc + bias ----
#pragma unroll
    for (int ii = 0; ii < 8; ++ii) {
        const int m0 = bm + wr * 128 + ii * 16 + q * 4;
#pragma unroll
        for (int j = 0; j < 4; ++j) {
            const int n = bn + wc * 64 + j * 16 + lr;
            const float bv = bias[n];
            float* cp = C + (size_t)m0 * O_DIM + n;
#pragma unroll
            for (int r = 0; r < 4; ++r)
                cp[(size_t)r * O_DIM] = acc[ii][j][r] + bv;
        }
    }
}

extern "C" void kernel_launch(void* const* d_in, const int* in_sizes, int n_in,
                              void* d_out, int out_size, void* d_ws, size_t ws_size,
                              hipStream_t stream) {
    const float* x        = (const float*)d_in[0];
    const float* weight   = (const float*)d_in[1];
    const float* codebook = (const float*)d_in[2];
    const float* bias     = (const float*)d_in[3];
    float* out = (float*)d_out;

    char* ws = (char*)d_ws;
    unsigned short* wq = (unsigned short*)ws;                               // 16 MB
    unsigned short* xb = (unsigned short*)(ws + (size_t)O_DIM * I_DIM * 2); // 64 MB

    fused_assign_kernel<<<O_DIM / 2, 256, 0, stream>>>(weight, codebook, wq);
    convert_kernel<<<((size_t)BS_TOK * I_DIM / 8) / 256, 256, 0, stream>>>(x, xb);
    gemm_8phase<<<256, 512, 0, stream>>>(xb, wq, bias, out);
}

// Round 3
// 403.501 us; speedup vs baseline: 1.0971x; 1.0971x over previous
//
#include <hip/hip_runtime.h>
#include <stdint.h>

#define O_DIM 2048
#define I_DIM 4096
#define BS_TOK 8192   // 4*2048 tokens
#define KCB 256
#define PQD 8

typedef __attribute__((ext_vector_type(8))) __bf16 bf16x8;
typedef __attribute__((ext_vector_type(4))) float f32x4;

static __device__ __forceinline__ unsigned short f32_to_bf16(float f) {
    unsigned int u = __float_as_uint(f);
    u += 0x7fffu + ((u >> 16) & 1u);   // round-to-nearest-even
    return (unsigned short)(u >> 16);
}

static __device__ __forceinline__ unsigned int pack2(unsigned short lo, unsigned short hi) {
    return (unsigned int)lo | ((unsigned int)hi << 16);
}

// ---------------- 1. fused rowscale+assignment AND x->bf16 convert ----------------
// Heterogeneous block roles (2 assign : 1 convert interleave) so the HBM-bound
// convert traffic drains underneath the VALU-bound assignment search.
// Assign path is numerically identical to the round-2-verified kernel.
#define TAU 1.5e-4f
#define CUT 3.0e-4f

__global__ __launch_bounds__(256) void assign_convert_kernel(const float* __restrict__ weight,
                                                             const float* __restrict__ codebook,
                                                             unsigned short* __restrict__ wq,
                                                             const float* __restrict__ x,
                                                             unsigned short* __restrict__ xb) {
    __shared__ __align__(16) float cb[KCB * PQD];   // 8 KB
    __shared__ float n2[KCB];                       // 1 KB
    __shared__ float red[4];

    const int bid = blockIdx.x;
    const int t = threadIdx.x;

    if ((bid % 3) == 2) {
        // ---- convert role: 512 blocks x 64K contiguous elems each ----
        const size_t base = (size_t)(bid / 3) * 65536 + (size_t)t * 8;
#pragma unroll 4
        for (int it = 0; it < 32; ++it) {
            size_t i = base + (size_t)it * 2048;
            float4 v0 = *(const float4*)(x + i);
            float4 v1 = *(const float4*)(x + i + 4);
            uint4 r;
            r.x = pack2(f32_to_bf16(v0.x), f32_to_bf16(v0.y));
            r.y = pack2(f32_to_bf16(v0.z), f32_to_bf16(v0.w));
            r.z = pack2(f32_to_bf16(v1.x), f32_to_bf16(v1.y));
            r.w = pack2(f32_to_bf16(v1.z), f32_to_bf16(v1.w));
            *(uint4*)(xb + i) = r;
        }
        return;
    }

    // ---- assign role: aid 0..1023, two output rows per block ----
    const int aid = (bid / 3) * 2 + (bid % 3);
    const int half = t >> 7;
    const int tid = t & 127;
    const int o = aid * 2 + half;

    const float* wp = weight + (size_t)o * I_DIM + tid * 32;
    float w[32];
#pragma unroll
    for (int q = 0; q < 8; ++q) {
        float4 v = *(const float4*)(wp + q * 4);
        w[q * 4 + 0] = v.x; w[q * 4 + 1] = v.y; w[q * 4 + 2] = v.z; w[q * 4 + 3] = v.w;
    }

    float4 c0 = *(const float4*)(codebook + t * PQD);
    float4 c1 = *(const float4*)(codebook + t * PQD + 4);
    *(float4*)&cb[t * PQD]     = c0;
    *(float4*)&cb[t * PQD + 4] = c1;
    double n2d = 0.0;
    n2d = fma((double)c0.x, (double)c0.x, n2d); n2d = fma((double)c0.y, (double)c0.y, n2d);
    n2d = fma((double)c0.z, (double)c0.z, n2d); n2d = fma((double)c0.w, (double)c0.w, n2d);
    n2d = fma((double)c1.x, (double)c1.x, n2d); n2d = fma((double)c1.y, (double)c1.y, n2d);
    n2d = fma((double)c1.z, (double)c1.z, n2d); n2d = fma((double)c1.w, (double)c1.w, n2d);
    n2[t] = (float)n2d;

    float m = 0.f;
#pragma unroll
    for (int i = 0; i < 32; ++i) m = fmaxf(m, fabsf(w[i]));
#pragma unroll
    for (int off = 32; off > 0; off >>= 1)
        m = fmaxf(m, __shfl_down(m, off, 64));
    int wave = t >> 6, lane = t & 63;
    if (lane == 0) red[wave] = m;
    __syncthreads();
    float s = fmaxf(fmaxf(red[half * 2], red[half * 2 + 1]), 1e-6f);

    float best[4] = {1e30f, 1e30f, 1e30f, 1e30f};
    float sec[4]  = {1e30f, 1e30f, 1e30f, 1e30f};
    int bi[4] = {0, 0, 0, 0};
#pragma unroll 2
    for (int c = 0; c < KCB; ++c) {
        float4 p0 = *(const float4*)&cb[c * PQD];
        float4 p1 = *(const float4*)&cb[c * PQD + 4];
        float t1 = s * n2[c];
#pragma unroll
        for (int k = 0; k < 4; ++k) {
            const float* wk = w + k * 8;
            float d = 0.f;
            d = fmaf(p0.x, wk[0], d); d = fmaf(p0.y, wk[1], d);
            d = fmaf(p0.z, wk[2], d); d = fmaf(p0.w, wk[3], d);
            d = fmaf(p1.x, wk[4], d); d = fmaf(p1.y, wk[5], d);
            d = fmaf(p1.z, wk[6], d); d = fmaf(p1.w, wk[7], d);
            float e = fmaf(-2.f, d, t1);
            bool lt = e < best[k];
            sec[k] = fminf(sec[k], lt ? best[k] : e);
            best[k] = fminf(best[k], e);
            bi[k] = lt ? c : bi[k];
        }
    }

#pragma unroll
    for (int k = 0; k < 4; ++k) {
        if (sec[k] - best[k] < TAU) {
            const float* wk = w + k * 8;
            double sd = (double)s;
            double g[PQD];
#pragma unroll
            for (int d = 0; d < PQD; ++d) g[d] = (double)wk[d] / sd;
            double bb = 1e300; int bbi = 0;
            float cut = best[k] + CUT;
            for (int c = 0; c < KCB; ++c) {
                float4 p0 = *(const float4*)&cb[c * PQD];
                float4 p1 = *(const float4*)&cb[c * PQD + 4];
                float d0 = 0.f;
                d0 = fmaf(p0.x, wk[0], d0); d0 = fmaf(p0.y, wk[1], d0);
                d0 = fmaf(p0.z, wk[2], d0); d0 = fmaf(p0.w, wk[3], d0);
                d0 = fmaf(p1.x, wk[4], d0); d0 = fmaf(p1.y, wk[5], d0);
                d0 = fmaf(p1.z, wk[6], d0); d0 = fmaf(p1.w, wk[7], d0);
                float e0 = fmaf(-2.f, d0, s * n2[c]);
                if (e0 <= cut) {
                    double n = 0.0, dot = 0.0;
#pragma unroll
                    for (int d = 0; d < PQD; ++d) {
                        double cv = (double)cb[c * PQD + d];
                        n = fma(cv, cv, n);
                        dot = fma(cv, g[d], dot);
                    }
                    double d2 = fma(-2.0, dot, n);
                    if (d2 < bb) { bb = d2; bbi = c; }
                }
            }
            bi[k] = bbi;
        }
    }

    unsigned short* dst = wq + (size_t)o * I_DIM + tid * 32;
#pragma unroll
    for (int k = 0; k < 4; ++k) {
        unsigned short u[8];
#pragma unroll
        for (int d = 0; d < PQD; ++d) u[d] = f32_to_bf16(cb[bi[k] * PQD + d] * s);
        uint4 r;
        r.x = pack2(u[0], u[1]); r.y = pack2(u[2], u[3]);
        r.z = pack2(u[4], u[5]); r.w = pack2(u[6], u[7]);
        *(uint4*)(dst + k * 8) = r;
    }
}

// ---------------- 2. 256x256 8-phase bf16 MFMA GEMM + bias (round-1 verified, 125 us) ----------------
#define GBM 256
#define GBN 256
#define NIT 32   // 32 iters x 2 K-tiles x 64 = 4096

#define LOFF_A(b,h) ((b)*32768 + (h)*8192)
#define LOFF_B(b,h) ((b)*32768 + 16384 + (h)*8192)

#define BARX() asm volatile("s_barrier" ::: "memory")
#define WAITV(n) asm volatile("s_waitcnt vmcnt(" #n ")" ::: "memory")

#define STAGE(P, h, kt, loff)                                                       \
  { _Pragma("unroll")                                                               \
    for (int l_ = 0; l_ < 2; ++l_) {                                                \
      const unsigned short* g_ = (P) + (size_t)((h) * 128 + l_ * 64) * I_DIM + (size_t)(kt) * 64; \
      unsigned short* d_ = (unsigned short*)&lds[(loff) + l_ * 4096 + wave * 512];  \
      __builtin_amdgcn_global_load_lds((const __attribute__((address_space(1))) void*)g_, \
                                       (__attribute__((address_space(3))) void*)d_, 16, 0, 0); \
    } }

#define READ_B(boff)                                                                \
  { _Pragma("unroll")                                                               \
    for (int kk_ = 0; kk_ < 2; ++kk_) {                                             \
      _Pragma("unroll")                                                             \
      for (int j_ = 0; j_ < 4; ++j_)                                                \
        bf[kk_][j_] = *(const bf16x8*)&lds[(boff) + baseB + j_ * 1024 + cxo[kk_]];  \
    } }

#define READ_A(boff, p)                                                             \
  { _Pragma("unroll")                                                               \
    for (int kk_ = 0; kk_ < 2; ++kk_) {                                             \
      _Pragma("unroll")                                                             \
      for (int ii_ = 0; ii_ < 2; ++ii_)                                             \
        af[kk_][ii_] = *(const bf16x8*)&lds[(boff) + baseA + (2 * (p) + ii_) * 1024 + cxo[kk_]]; \
    } }

#define MFMA_Q(p)                                                                   \
  { __builtin_amdgcn_s_setprio(1);                                                  \
    _Pragma("unroll")                                                               \
    for (int ii_ = 0; ii_ < 2; ++ii_) {                                             \
      _Pragma("unroll")                                                             \
      for (int j_ = 0; j_ < 4; ++j_) {                                              \
        _Pragma("unroll")                                                           \
        for (int kk_ = 0; kk_ < 2; ++kk_)                                           \
          acc[2 * (p) + ii_][j_] = __builtin_amdgcn_mfma_f32_16x16x32_bf16(         \
              af[kk_][ii_], bf[kk_][j_], acc[2 * (p) + ii_][j_], 0, 0, 0);          \
      }                                                                             \
    }                                                                               \
    __builtin_amdgcn_s_setprio(0); }

__global__ __launch_bounds__(512, 2) void gemm_8phase(const unsigned short* __restrict__ A, // [BS_TOK][I]
                                                      const unsigned short* __restrict__ B, // [O_DIM][I]
                                                      const float* __restrict__ bias,
                                                      float* __restrict__ C) {
    __shared__ __align__(16) unsigned short lds[65536];   // 128 KiB: 2 bufs x (A 256x64 + B 256x64)

    const int t = threadIdx.x;
    const int wave = t >> 6;
    const int lane = t & 63;
    const int q = lane >> 4;
    const int lr = lane & 15;
    const int wr = wave >> 2;   // 0..1 (M)
    const int wc = wave & 3;    // 0..3 (N)

    // bijective XCD swizzle: 256 wgs, XCD x owns column-panel tn=x (B panel 2MB -> L2)
    const int swz = (((int)blockIdx.x & 7) * 32) + ((int)blockIdx.x >> 3);
    const int bm = (swz & 31) * GBM;
    const int bn = (swz >> 5) * GBN;

    // staging: thread t covers row (l*64 + t/8), 16B chunk (t%8); source chunk
    // pre-swizzled by ^(row&7) so LDS stays linear (rule #21)
    const int trow = t >> 3;
    const int csw = ((t & 7) ^ (trow & 7)) * 8;
    const unsigned short* pa = A + (size_t)(bm + trow) * I_DIM + csw;
    const unsigned short* pb = B + (size_t)(bn + trow) * I_DIM + csw;

    // read bases (shorts)
    const int baseA = wr * 8192 + lr * 64;
    const int baseB = 16384 + (wc >> 1) * 8192 + ((wc & 1) * 64 + lr) * 64;
    const int cxo[2] = { (q ^ (lr & 7)) * 8, ((4 + q) ^ (lr & 7)) * 8 };

    f32x4 acc[8][4] = {};
    bf16x8 bf[2][4];
    bf16x8 af[2][2];

    // ---- prologue: tile0 (buf0, 4 halves) + tile1.B (buf1) ----
    STAGE(pa, 0, 0, LOFF_A(0, 0));
    STAGE(pa, 1, 0, LOFF_A(0, 1));
    STAGE(pb, 0, 0, LOFF_B(0, 0));
    STAGE(pb, 1, 0, LOFF_B(0, 1));
    STAGE(pb, 0, 1, LOFF_B(1, 0));
    STAGE(pb, 1, 1, LOFF_B(1, 1));
    WAITV(4);          // tile0 landed; tile1.B (4 loads) stays in flight
    BARX();

#pragma unroll 1
    for (int i = 0; i < NIT; ++i) {
        const int kO  = 2 * i + 1;
        const int kN  = 2 * i + 2;
        const int kN1 = 2 * i + 3;
        const bool nl = (i < NIT - 1);

        // P0: tile E quad0 (buf0); stage O.A0 -> buf1.A0
        READ_B(0);
        READ_A(0, 0);
        STAGE(pa, 0, kO, LOFF_A(1, 0));
        BARX();
        MFMA_Q(0);
        BARX();

        // P1: quad1; stage O.A1 -> buf1.A1 ; (E+2).B0 -> buf0.B0
        READ_A(0, 1);
        STAGE(pa, 1, kO, LOFF_A(1, 1));
        if (nl) STAGE(pb, 0, kN, LOFF_B(0, 0));
        BARX();
        MFMA_Q(1);
        BARX();

        // P2: quad2; stage (E+2).B1 -> buf0.B1
        READ_A(0, 2);
        if (nl) STAGE(pb, 1, kN, LOFF_B(0, 1));
        BARX();
        MFMA_Q(2);
        BARX();

        // P3: quad3; counted wait covers tile O (A+B landed)
        READ_A(0, 3);
        BARX();
        MFMA_Q(3);
        if (nl) { WAITV(4); } else { WAITV(0); }
        BARX();

        // P4: tile O quad0 (buf1); stage (E+2).A0 -> buf0.A0
        READ_B(32768);
        READ_A(32768, 0);
        if (nl) STAGE(pa, 0, kN, LOFF_A(0, 0));
        BARX();
        MFMA_Q(0);
        BARX();

        // P5: quad1; stage (E+2).A1 -> buf0.A1
        READ_A(32768, 1);
        if (nl) STAGE(pa, 1, kN, LOFF_A(0, 1));
        BARX();
        MFMA_Q(1);
        BARX();

        // P6: quad2; stage (O+2).B0 -> buf1.B0
        READ_A(32768, 2);
        if (nl) STAGE(pb, 0, kN1, LOFF_B(1, 0));
        BARX();
        MFMA_Q(2);
        BARX();

        // P7: quad3; counted wait covers tile E+2 (buf0 complete)
        READ_A(32768, 3);
        if (nl) STAGE(pb, 1, kN1, LOFF_B(1, 1));
        BARX();
        MFMA_Q(3);
        WAITV(4);   // no-op on last iter (0 outstanding)
        BARX();
    }

    // ---- epilogue: C = acc + bias ----
#pragma unroll
    for (int ii = 0; ii < 8; ++ii) {
        const int m0 = bm + wr * 128 + ii * 16 + q * 4;
#pragma unroll
        for (int j = 0; j < 4; ++j) {
            const int n = bn + wc * 64 + j * 16 + lr;
            const float bv = bias[n];
            float* cp = C + (size_t)m0 * O_DIM + n;
#pragma unroll
            for (int r = 0; r < 4; ++r)
                cp[(size_t)r * O_DIM] = acc[ii][j][r] + bv;
        }
    }
}

extern "C" void kernel_launch(void* const* d_in, const int* in_sizes, int n_in,
                              void* d_out, int out_size, void* d_ws, size_t ws_size,
                              hipStream_t stream) {
    const float* x        = (const float*)d_in[0];
    const float* weight   = (const float*)d_in[1];
    const float* codebook = (const float*)d_in[2];
    const float* bias     = (const float*)d_in[3];
    float* out = (float*)d_out;

    char* ws = (char*)d_ws;
    unsigned short* wq = (unsigned short*)ws;                               // 16 MB
    unsigned short* xb = (unsigned short*)(ws + (size_t)O_DIM * I_DIM * 2); // 64 MB

    assign_convert_kernel<<<1536, 256, 0, stream>>>(weight, codebook, wq, x, xb);
    gemm_8phase<<<256, 512, 0, stream>>>(xb, wq, bias, out);
}